// Round 3
// baseline (702.941 us; speedup 1.0000x reference)
//
#include <hip/hip_runtime.h>
#include <hip/hip_bf16.h>

#define H   128
#define ND  64
#define SCAN_B 256
#define TILE_R 64

typedef __bf16  bf16x8 __attribute__((ext_vector_type(8)));
typedef float   f32x4  __attribute__((ext_vector_type(4)));

__device__ __forceinline__ unsigned short f2bf(float f) {
  return __bfloat16_as_ushort(__float2bfloat16(f));
}
__device__ __forceinline__ float bf2f(unsigned short u) {
  return __uint_as_float(((unsigned int)u) << 16);
}

// ---------------- CSR build ----------------

__global__ __launch_bounds__(256) void count_deg_k(const int* __restrict__ dst,
                                                   int* __restrict__ cnt, int E) {
  int e = blockIdx.x * 256 + threadIdx.x;
  if (e < E) atomicAdd(&cnt[dst[e]], 1);
}

__global__ __launch_bounds__(SCAN_B) void scan1_k(const int* __restrict__ cnt,
                                                  int* __restrict__ off,
                                                  int* __restrict__ bsums, int n) {
  __shared__ int tmp[SCAN_B];
  int tid = threadIdx.x;
  int gid = blockIdx.x * SCAN_B + tid;
  int v = (gid < n) ? cnt[gid] : 0;
  tmp[tid] = v;
  __syncthreads();
  for (int o = 1; o < SCAN_B; o <<= 1) {
    int t = (tid >= o) ? tmp[tid - o] : 0;
    __syncthreads();
    tmp[tid] += t;
    __syncthreads();
  }
  if (gid < n) off[gid] = tmp[tid] - v;          // exclusive
  if (tid == SCAN_B - 1) bsums[blockIdx.x] = tmp[tid];
}

__global__ __launch_bounds__(SCAN_B) void scan2_k(int* __restrict__ bsums, int nb) {
  __shared__ int tmp[SCAN_B];
  int tid = threadIdx.x;
  int v = (tid < nb) ? bsums[tid] : 0;
  tmp[tid] = v;
  __syncthreads();
  for (int o = 1; o < SCAN_B; o <<= 1) {
    int t = (tid >= o) ? tmp[tid - o] : 0;
    __syncthreads();
    tmp[tid] += t;
    __syncthreads();
  }
  if (tid < nb) bsums[tid] = tmp[tid] - v;       // exclusive block offsets
}

__global__ __launch_bounds__(SCAN_B) void scan3_k(int* __restrict__ off,
                                                  const int* __restrict__ bsums,
                                                  int* __restrict__ cur,
                                                  int n, int e_total) {
  int gid = blockIdx.x * SCAN_B + threadIdx.x;
  if (gid < n) {
    int o = off[gid] + bsums[blockIdx.x];
    off[gid] = o;
    cur[gid] = o;
  }
  if (gid == 0) off[n] = e_total;
}

__global__ __launch_bounds__(256) void scatter_k(const int* __restrict__ src,
                                                 const int* __restrict__ dst,
                                                 int* __restrict__ cur,
                                                 int* __restrict__ ssrc, int E) {
  int e = blockIdx.x * 256 + threadIdx.x;
  if (e < E) {
    int d = dst[e];
    int p = atomicAdd(&cur[d], 1);
    ssrc[p] = src[e];
  }
}

// ---------------- Wg fragment prep ----------------
// Pack Wg[l] (fp32 [K][N]) into MFMA-B fragment order, bf16:
// chunk c = (nt*4+ks)*64 + lane; content j=0..7: Wg[l][ks*32+(lane>>4)*8+j][nt*16+(lane&15)]

__global__ __launch_bounds__(256) void prep_wfrag_k(const float* __restrict__ Wg,
                                                    unsigned short* __restrict__ wfrag) {
  int l = blockIdx.x;
  const float* W = Wg + (size_t)l * H * H;
  __shared__ float sW[H * H];                     // 64 KB
  for (int i = threadIdx.x; i < H * H; i += 256) sW[i] = W[i];
  __syncthreads();
  unsigned short* out = wfrag + (size_t)l * 2048 * 8;
  for (int c = threadIdx.x; c < 2048; c += 256) {
    int lane = c & 63;
    int combo = c >> 6;               // nt*4+ks
    int nt = combo >> 2, ks = combo & 3;
    int n = nt * 16 + (lane & 15);
    int kb = ks * 32 + (lane >> 4) * 8;
    unsigned short* o = out + (size_t)c * 8;
#pragma unroll
    for (int j = 0; j < 8; ++j) o[j] = f2bf(sW[(kb + j) * H + n]);
  }
}

// ---------------- node projection: h = x @ Wp + bp ----------------

__global__ __launch_bounds__(256, 2) void node_proj_k(const float* __restrict__ x,
                                                      const float* __restrict__ Wp,
                                                      const float* __restrict__ bp,
                                                      float* __restrict__ h,
                                                      unsigned short* __restrict__ hb,
                                                      int n) {
  __shared__ float sW[ND * H];                    // 32 KB
  for (int i = threadIdx.x; i < ND * H; i += 256) sW[i] = Wp[i];
  __syncthreads();
  const float4* sW4 = (const float4*)sW;
  int cg = threadIdx.x & 31;                      // cols 4cg..4cg+3
  int rg = threadIdx.x >> 5;                      // rows 8rg..8rg+7 within tile
  float4 bv = ((const float4*)bp)[cg];
  int ntiles = (n + TILE_R - 1) / TILE_R;
  for (int t = blockIdx.x; t < ntiles; t += gridDim.x) {
    int row0 = t * TILE_R + rg * 8;
    if (row0 >= n) continue;                      // whole 8-row group out of range
    const float* Ab = x + (size_t)row0 * ND;      // row0+7 < n guaranteed (n % 8 == 0 here; guarded below anyway)
    float4 acc[8] = {};
#pragma unroll
    for (int k4 = 0; k4 < 16; ++k4) {
      float4 b0 = sW4[(4 * k4 + 0) * 32 + cg];
      float4 b1 = sW4[(4 * k4 + 1) * 32 + cg];
      float4 b2 = sW4[(4 * k4 + 2) * 32 + cg];
      float4 b3 = sW4[(4 * k4 + 3) * 32 + cg];
#pragma unroll
      for (int i = 0; i < 8; ++i) {
        float4 a = *(const float4*)(Ab + i * ND + k4 * 4);
        acc[i].x += a.x * b0.x + a.y * b1.x + a.z * b2.x + a.w * b3.x;
        acc[i].y += a.x * b0.y + a.y * b1.y + a.z * b2.y + a.w * b3.y;
        acc[i].z += a.x * b0.z + a.y * b1.z + a.z * b2.z + a.w * b3.z;
        acc[i].w += a.x * b0.w + a.y * b1.w + a.z * b2.w + a.w * b3.w;
      }
    }
#pragma unroll
    for (int i = 0; i < 8; ++i) {
      int row = row0 + i;
      if (row < n) {
        float4 o;
        o.x = acc[i].x + bv.x; o.y = acc[i].y + bv.y;
        o.z = acc[i].z + bv.z; o.w = acc[i].w + bv.w;
        *(float4*)(h + (size_t)row * H + cg * 4) = o;
        ushort4 us = make_ushort4(f2bf(o.x), f2bf(o.y), f2bf(o.z), f2bf(o.w));
        *(ushort4*)(hb + (size_t)row * H + cg * 4) = us;
      }
    }
  }
}

// ---------------- aggregation (bf16 gather -> bf16 msg) ----------------
// half-wave (32 lanes) per node row (256 B bf16); fp32 accumulate.

__global__ __launch_bounds__(256) void aggregate_bf_k(const unsigned short* __restrict__ hb,
                                                      const int* __restrict__ off,
                                                      const int* __restrict__ ssrc,
                                                      unsigned short* __restrict__ msgb,
                                                      int n) {
  int node = blockIdx.x * 8 + (threadIdx.x >> 5);
  if (node >= n) return;
  int l = threadIdx.x & 31;
  int beg = off[node], end = off[node + 1];
  float4 acc = {0.f, 0.f, 0.f, 0.f};
  int e = beg;
  for (; e + 4 <= end; e += 4) {
    int s0 = ssrc[e], s1 = ssrc[e + 1], s2 = ssrc[e + 2], s3 = ssrc[e + 3];
    ushort4 v0 = ((const ushort4*)(hb + (size_t)s0 * H))[l];
    ushort4 v1 = ((const ushort4*)(hb + (size_t)s1 * H))[l];
    ushort4 v2 = ((const ushort4*)(hb + (size_t)s2 * H))[l];
    ushort4 v3 = ((const ushort4*)(hb + (size_t)s3 * H))[l];
    acc.x += bf2f(v0.x) + bf2f(v1.x) + bf2f(v2.x) + bf2f(v3.x);
    acc.y += bf2f(v0.y) + bf2f(v1.y) + bf2f(v2.y) + bf2f(v3.y);
    acc.z += bf2f(v0.z) + bf2f(v1.z) + bf2f(v2.z) + bf2f(v3.z);
    acc.w += bf2f(v0.w) + bf2f(v1.w) + bf2f(v2.w) + bf2f(v3.w);
  }
  for (; e < end; ++e) {
    int s0 = ssrc[e];
    ushort4 v0 = ((const ushort4*)(hb + (size_t)s0 * H))[l];
    acc.x += bf2f(v0.x); acc.y += bf2f(v0.y);
    acc.z += bf2f(v0.z); acc.w += bf2f(v0.w);
  }
  float inv = (end > beg) ? 1.0f / (float)(end - beg) : 0.f;
  ushort4 o = make_ushort4(f2bf(acc.x * inv), f2bf(acc.y * inv),
                           f2bf(acc.z * inv), f2bf(acc.w * inv));
  ((ushort4*)(msgb + (size_t)node * H))[l] = o;
}

// ---------------- layer update via MFMA: h = relu(h + msg @ Wg + bg) --------
// One 64-row tile per block; 4 waves, wave w -> rows row0+w*16 .. +15.
// B (Wg^T bf16) staged in LDS in fragment order (conflict-free ds_read_b128).
// A frags straight from global msgb. C/D layout: col=lane&15, row=quad*4+reg.

__global__ __launch_bounds__(256, 4) void layer_update_mfma_k(
    float* __restrict__ h, unsigned short* __restrict__ hb,
    const unsigned short* __restrict__ msgb,
    const unsigned short* __restrict__ wfrag,
    const float* __restrict__ bg, int n) {
  __shared__ unsigned short sB[2048 * 8];         // 32 KB, fragment order
  const uint4* wsrc = (const uint4*)wfrag;
  uint4* sB4 = (uint4*)sB;
  for (int i = threadIdx.x; i < 2048; i += 256) sB4[i] = wsrc[i];
  __syncthreads();

  int wave = threadIdx.x >> 6, lane = threadIdx.x & 63;
  int quad = lane >> 4, n16 = lane & 15;
  int row0 = blockIdx.x * 64 + wave * 16;

  // A fragments: lane holds A[m=lane&15][k=quad*8+j] for each 32-wide k-step
  union { uint4 u; bf16x8 b; } af[4];
  const uint4* arow = (const uint4*)(msgb + (size_t)(row0 + n16) * H);
#pragma unroll
  for (int ks = 0; ks < 4; ++ks) af[ks].u = arow[ks * 4 + quad];

  f32x4 acc[8] = {};
#pragma unroll
  for (int nt = 0; nt < 8; ++nt) {
#pragma unroll
    for (int ks = 0; ks < 4; ++ks) {
      union { uint4 u; bf16x8 b; } bf_;
      bf_.u = sB4[(nt * 4 + ks) * 64 + lane];
      acc[nt] = __builtin_amdgcn_mfma_f32_16x16x32_bf16(af[ks].b, bf_.b, acc[nt], 0, 0, 0);
    }
  }

#pragma unroll
  for (int nt = 0; nt < 8; ++nt) {
    int col = nt * 16 + n16;
    float bias = bg[col];
#pragma unroll
    for (int r = 0; r < 4; ++r) {
      int row = row0 + quad * 4 + r;
      if (row < n) {
        float* hp = h + (size_t)row * H + col;
        float v = *hp + acc[nt][r] + bias;
        v = v > 0.f ? v : 0.f;
        *hp = v;
        hb[(size_t)row * H + col] = f2bf(v);
      }
    }
  }
}

// ---------------- global mean pool ----------------

__global__ __launch_bounds__(256) void reduce_mean_k(const float* __restrict__ h,
                                                     float* __restrict__ gsum, int n) {
  __shared__ float s[256];
  int col  = threadIdx.x & 127;
  int half = threadIdx.x >> 7;
  float acc = 0.f;
  for (int row = blockIdx.x * 2 + half; row < n; row += gridDim.x * 2)
    acc += h[(size_t)row * H + col];
  s[threadIdx.x] = acc;
  __syncthreads();
  if (threadIdx.x < 128) atomicAdd(&gsum[col], s[col] + s[col + 128]);
}

// ---------------- MLP head ----------------

__global__ __launch_bounds__(256) void mlp_k(const float* __restrict__ gsum,
                                             const float* __restrict__ W1,
                                             const float* __restrict__ b1,
                                             const float* __restrict__ W2,
                                             const float* __restrict__ b2,
                                             float* __restrict__ out, float invN) {
  __shared__ float g[H];
  __shared__ float hid[H];
  int tid = threadIdx.x;
  if (tid < H) g[tid] = gsum[tid] * invN;
  __syncthreads();
  if (tid < H) {
    float acc = b1[tid];
    for (int k = 0; k < H; ++k) acc += g[k] * W1[k * H + tid];
    hid[tid] = acc > 0.f ? acc : 0.f;
  }
  __syncthreads();
  float acc = b2[tid];
  for (int k = 0; k < H; ++k) acc += hid[k] * W2[k * 256 + tid];
  out[tid] = acc;
}

// ---------------- launcher ----------------

extern "C" void kernel_launch(void* const* d_in, const int* in_sizes, int n_in,
                              void* d_out, int out_size, void* d_ws, size_t ws_size,
                              hipStream_t stream) {
  const float* x  = (const float*)d_in[0];
  const int*   src = (const int*)d_in[1];
  const int*   dst = (const int*)d_in[2];
  const float* Wp = (const float*)d_in[3];
  const float* bp = (const float*)d_in[4];
  const float* Wg = (const float*)d_in[5];
  const float* bg = (const float*)d_in[6];
  const float* W1 = (const float*)d_in[7];
  const float* b1 = (const float*)d_in[8];
  const float* W2 = (const float*)d_in[9];
  const float* b2 = (const float*)d_in[10];
  float* out = (float*)d_out;

  const int N = in_sizes[0] / ND;   // 50000
  const int E = in_sizes[1];        // 800000
  const int N_pad = ((N + TILE_R - 1) / TILE_R) * TILE_R;  // 50048
  const size_t NH = (size_t)N_pad * H;

  char* p = (char*)d_ws;
  float* h = (float*)p;                 p += NH * sizeof(float);
  unsigned short* hb = (unsigned short*)p;   p += NH * sizeof(unsigned short);
  unsigned short* msgb = (unsigned short*)p; p += NH * sizeof(unsigned short);
  unsigned short* wfrag = (unsigned short*)p; p += 3 * 2048 * 8 * sizeof(unsigned short);
  int*   off  = (int*)p;   p += (size_t)(N + 1) * sizeof(int);
  int*   cur  = (int*)p;   p += (size_t)N * sizeof(int);
  int*   ssrc = (int*)p;   p += (size_t)E * sizeof(int);
  float* gsum = (float*)p; p += H * sizeof(float);
  int*   bsums= (int*)p;   p += 256 * sizeof(int);

  const int nb = (N + SCAN_B - 1) / SCAN_B;
  const int ntiles = N_pad / TILE_R;    // 782

  // CSR build
  hipMemsetAsync(cur, 0, (size_t)N * sizeof(int), stream);
  count_deg_k<<<(E + 255) / 256, 256, 0, stream>>>(dst, cur, E);
  scan1_k<<<nb, SCAN_B, 0, stream>>>(cur, off, bsums, N);
  scan2_k<<<1, SCAN_B, 0, stream>>>(bsums, nb);
  scan3_k<<<nb, SCAN_B, 0, stream>>>(off, bsums, cur, N, E);
  scatter_k<<<(E + 255) / 256, 256, 0, stream>>>(src, dst, cur, ssrc, E);

  // weight fragment prep (independent of CSR)
  prep_wfrag_k<<<3, 256, 0, stream>>>(Wg, wfrag);

  // node projection
  node_proj_k<<<512, 256, 0, stream>>>(x, Wp, bp, h, hb, N);

  // 3 GNN layers
  for (int l = 0; l < 3; ++l) {
    aggregate_bf_k<<<(N + 7) / 8, 256, 0, stream>>>(hb, off, ssrc, msgb, N);
    layer_update_mfma_k<<<ntiles, 256, 0, stream>>>(h, hb, msgb,
                                                    wfrag + (size_t)l * 2048 * 8,
                                                    bg + (size_t)l * H, N);
  }

  // mean pool + MLP head
  hipMemsetAsync(gsum, 0, H * sizeof(float), stream);
  reduce_mean_k<<<256, 256, 0, stream>>>(h, gsum, N);
  mlp_k<<<1, 256, 0, stream>>>(gsum, W1, b1, W2, b2, out, 1.0f / (float)N);
}

// Round 4
// 390.450 us; speedup vs baseline: 1.8003x; 1.8003x over previous
//
#include <hip/hip_runtime.h>
#include <hip/hip_bf16.h>

#define H   128
#define ND  64
#define SCAN_B 256
#define TILE_R 64

typedef __bf16  bf16x8 __attribute__((ext_vector_type(8)));
typedef float   f32x4  __attribute__((ext_vector_type(4)));

__device__ __forceinline__ unsigned short f2bf(float f) {
  return __bfloat16_as_ushort(__float2bfloat16(f));
}
__device__ __forceinline__ float bf2f(unsigned short u) {
  return __uint_as_float(((unsigned int)u) << 16);
}

// ---------------- CSR build ----------------

__global__ __launch_bounds__(256) void count_deg_k(const int* __restrict__ dst,
                                                   int* __restrict__ cnt, int E) {
  int e = blockIdx.x * 256 + threadIdx.x;
  if (e < E) atomicAdd(&cnt[dst[e]], 1);
}

__global__ __launch_bounds__(SCAN_B) void scan1_k(const int* __restrict__ cnt,
                                                  int* __restrict__ off,
                                                  int* __restrict__ bsums, int n) {
  __shared__ int tmp[SCAN_B];
  int tid = threadIdx.x;
  int gid = blockIdx.x * SCAN_B + tid;
  int v = (gid < n) ? cnt[gid] : 0;
  tmp[tid] = v;
  __syncthreads();
  for (int o = 1; o < SCAN_B; o <<= 1) {
    int t = (tid >= o) ? tmp[tid - o] : 0;
    __syncthreads();
    tmp[tid] += t;
    __syncthreads();
  }
  if (gid < n) off[gid] = tmp[tid] - v;          // exclusive
  if (tid == SCAN_B - 1) bsums[blockIdx.x] = tmp[tid];
}

__global__ __launch_bounds__(SCAN_B) void scan2_k(int* __restrict__ bsums, int nb) {
  __shared__ int tmp[SCAN_B];
  int tid = threadIdx.x;
  int v = (tid < nb) ? bsums[tid] : 0;
  tmp[tid] = v;
  __syncthreads();
  for (int o = 1; o < SCAN_B; o <<= 1) {
    int t = (tid >= o) ? tmp[tid - o] : 0;
    __syncthreads();
    tmp[tid] += t;
    __syncthreads();
  }
  if (tid < nb) bsums[tid] = tmp[tid] - v;       // exclusive block offsets
}

__global__ __launch_bounds__(SCAN_B) void scan3_k(int* __restrict__ off,
                                                  const int* __restrict__ bsums,
                                                  int* __restrict__ cur,
                                                  int n, int e_total) {
  int gid = blockIdx.x * SCAN_B + threadIdx.x;
  if (gid < n) {
    int o = off[gid] + bsums[blockIdx.x];
    off[gid] = o;
    cur[gid] = o;
  }
  if (gid == 0) off[n] = e_total;
}

__global__ __launch_bounds__(256) void scatter_k(const int* __restrict__ src,
                                                 const int* __restrict__ dst,
                                                 int* __restrict__ cur,
                                                 int* __restrict__ ssrc, int E) {
  int e = blockIdx.x * 256 + threadIdx.x;
  if (e < E) {
    int d = dst[e];
    int p = atomicAdd(&cur[d], 1);
    ssrc[p] = src[e];
  }
}

// ---------------- x -> bf16 cast ----------------

__global__ __launch_bounds__(256) void cast_bf_k(const float* __restrict__ x,
                                                 unsigned short* __restrict__ xb,
                                                 int total4) {
  int i = blockIdx.x * 256 + threadIdx.x;
  if (i < total4) {
    float4 v = ((const float4*)x)[i];
    ((ushort4*)xb)[i] = make_ushort4(f2bf(v.x), f2bf(v.y), f2bf(v.z), f2bf(v.w));
  }
}

// ---------------- weight fragment prep ----------------
// Pack W (fp32 [K][H], K = 64 or 128) into MFMA-B fragment order, bf16:
// chunk c = (nt*KS+ks)*64 + lane; j=0..7: W[ks*32+(lane>>4)*8+j][nt*16+(lane&15)]

__global__ __launch_bounds__(256) void prep_wfrag_k(const float* __restrict__ Wg,
                                                    unsigned short* __restrict__ wfrag) {
  int l = blockIdx.x;
  const float* W = Wg + (size_t)l * H * H;
  __shared__ float sW[H * H];                     // 64 KB
  for (int i = threadIdx.x; i < H * H; i += 256) sW[i] = W[i];
  __syncthreads();
  unsigned short* out = wfrag + (size_t)l * 2048 * 8;
  for (int c = threadIdx.x; c < 2048; c += 256) {
    int lane = c & 63;
    int combo = c >> 6;               // nt*4+ks
    int nt = combo >> 2, ks = combo & 3;
    int n = nt * 16 + (lane & 15);
    int kb = ks * 32 + (lane >> 4) * 8;
    unsigned short* o = out + (size_t)c * 8;
#pragma unroll
    for (int j = 0; j < 8; ++j) o[j] = f2bf(sW[(kb + j) * H + n]);
  }
}

__global__ __launch_bounds__(256) void prep_wpfrag_k(const float* __restrict__ Wp,
                                                     unsigned short* __restrict__ wpfrag) {
  __shared__ float sW[ND * H];                    // 32 KB
  for (int i = threadIdx.x; i < ND * H; i += 256) sW[i] = Wp[i];
  __syncthreads();
  for (int c = threadIdx.x; c < 1024; c += 256) {
    int lane = c & 63;
    int combo = c >> 6;               // nt*2+ks
    int nt = combo >> 1, ks = combo & 1;
    int n = nt * 16 + (lane & 15);
    int kb = ks * 32 + (lane >> 4) * 8;
    unsigned short* o = wpfrag + (size_t)c * 8;
#pragma unroll
    for (int j = 0; j < 8; ++j) o[j] = f2bf(sW[(kb + j) * H + n]);
  }
}

// ---------------- node projection via MFMA: h = x @ Wp + bp ----------------
// One 64-row tile/block, 4 waves; A frags from xb (64 distinct addrs/instr,
// each 128-B xb row fetched exactly once); B staged in 16 KB LDS.

__global__ __launch_bounds__(256, 4) void node_proj_mfma_k(
    const unsigned short* __restrict__ xb,
    const unsigned short* __restrict__ wpfrag,
    const float* __restrict__ bp,
    float* __restrict__ h, unsigned short* __restrict__ hb, int n) {
  __shared__ unsigned short sB[1024 * 8];         // 16 KB, fragment order
  const uint4* wsrc = (const uint4*)wpfrag;
  uint4* sB4 = (uint4*)sB;
  for (int i = threadIdx.x; i < 1024; i += 256) sB4[i] = wsrc[i];
  __syncthreads();

  int wave = threadIdx.x >> 6, lane = threadIdx.x & 63;
  int quad = lane >> 4, n16 = lane & 15;
  int row0 = blockIdx.x * 64 + wave * 16;

  union { uint4 u; bf16x8 b; } af[2];
  const uint4* arow = (const uint4*)(xb + (size_t)(row0 + n16) * ND);
#pragma unroll
  for (int ks = 0; ks < 2; ++ks) af[ks].u = arow[ks * 4 + quad];

  f32x4 acc[8] = {};
#pragma unroll
  for (int nt = 0; nt < 8; ++nt) {
#pragma unroll
    for (int ks = 0; ks < 2; ++ks) {
      union { uint4 u; bf16x8 b; } bf_;
      bf_.u = sB4[(nt * 2 + ks) * 64 + lane];
      acc[nt] = __builtin_amdgcn_mfma_f32_16x16x32_bf16(af[ks].b, bf_.b, acc[nt], 0, 0, 0);
    }
  }

#pragma unroll
  for (int nt = 0; nt < 8; ++nt) {
    int col = nt * 16 + n16;
    float bias = bp[col];
#pragma unroll
    for (int r = 0; r < 4; ++r) {
      int row = row0 + quad * 4 + r;
      if (row < n) {
        float v = acc[nt][r] + bias;               // no relu in projection
        h[(size_t)row * H + col] = v;
        hb[(size_t)row * H + col] = f2bf(v);
      }
    }
  }
}

// ---------------- aggregation (bf16 gather -> bf16 msg) ----------------
// half-wave (32 lanes) per node row (256 B bf16); fp32 accumulate.

__global__ __launch_bounds__(256) void aggregate_bf_k(const unsigned short* __restrict__ hb,
                                                      const int* __restrict__ off,
                                                      const int* __restrict__ ssrc,
                                                      unsigned short* __restrict__ msgb,
                                                      int n) {
  int node = blockIdx.x * 8 + (threadIdx.x >> 5);
  if (node >= n) return;
  int l = threadIdx.x & 31;
  int beg = off[node], end = off[node + 1];
  float4 acc = {0.f, 0.f, 0.f, 0.f};
  int e = beg;
  for (; e + 4 <= end; e += 4) {
    int s0 = ssrc[e], s1 = ssrc[e + 1], s2 = ssrc[e + 2], s3 = ssrc[e + 3];
    ushort4 v0 = ((const ushort4*)(hb + (size_t)s0 * H))[l];
    ushort4 v1 = ((const ushort4*)(hb + (size_t)s1 * H))[l];
    ushort4 v2 = ((const ushort4*)(hb + (size_t)s2 * H))[l];
    ushort4 v3 = ((const ushort4*)(hb + (size_t)s3 * H))[l];
    acc.x += bf2f(v0.x) + bf2f(v1.x) + bf2f(v2.x) + bf2f(v3.x);
    acc.y += bf2f(v0.y) + bf2f(v1.y) + bf2f(v2.y) + bf2f(v3.y);
    acc.z += bf2f(v0.z) + bf2f(v1.z) + bf2f(v2.z) + bf2f(v3.z);
    acc.w += bf2f(v0.w) + bf2f(v1.w) + bf2f(v2.w) + bf2f(v3.w);
  }
  for (; e < end; ++e) {
    int s0 = ssrc[e];
    ushort4 v0 = ((const ushort4*)(hb + (size_t)s0 * H))[l];
    acc.x += bf2f(v0.x); acc.y += bf2f(v0.y);
    acc.z += bf2f(v0.z); acc.w += bf2f(v0.w);
  }
  float inv = (end > beg) ? 1.0f / (float)(end - beg) : 0.f;
  ushort4 o = make_ushort4(f2bf(acc.x * inv), f2bf(acc.y * inv),
                           f2bf(acc.z * inv), f2bf(acc.w * inv));
  ((ushort4*)(msgb + (size_t)node * H))[l] = o;
}

// ---------------- layer update via MFMA: h = relu(h + msg @ Wg + bg) --------

__global__ __launch_bounds__(256, 4) void layer_update_mfma_k(
    float* __restrict__ h, unsigned short* __restrict__ hb,
    const unsigned short* __restrict__ msgb,
    const unsigned short* __restrict__ wfrag,
    const float* __restrict__ bg, int n) {
  __shared__ unsigned short sB[2048 * 8];         // 32 KB, fragment order
  const uint4* wsrc = (const uint4*)wfrag;
  uint4* sB4 = (uint4*)sB;
  for (int i = threadIdx.x; i < 2048; i += 256) sB4[i] = wsrc[i];
  __syncthreads();

  int wave = threadIdx.x >> 6, lane = threadIdx.x & 63;
  int quad = lane >> 4, n16 = lane & 15;
  int row0 = blockIdx.x * 64 + wave * 16;

  union { uint4 u; bf16x8 b; } af[4];
  const uint4* arow = (const uint4*)(msgb + (size_t)(row0 + n16) * H);
#pragma unroll
  for (int ks = 0; ks < 4; ++ks) af[ks].u = arow[ks * 4 + quad];

  f32x4 acc[8] = {};
#pragma unroll
  for (int nt = 0; nt < 8; ++nt) {
#pragma unroll
    for (int ks = 0; ks < 4; ++ks) {
      union { uint4 u; bf16x8 b; } bf_;
      bf_.u = sB4[(nt * 4 + ks) * 64 + lane];
      acc[nt] = __builtin_amdgcn_mfma_f32_16x16x32_bf16(af[ks].b, bf_.b, acc[nt], 0, 0, 0);
    }
  }

#pragma unroll
  for (int nt = 0; nt < 8; ++nt) {
    int col = nt * 16 + n16;
    float bias = bg[col];
#pragma unroll
    for (int r = 0; r < 4; ++r) {
      int row = row0 + quad * 4 + r;
      if (row < n) {
        float* hp = h + (size_t)row * H + col;
        float v = *hp + acc[nt][r] + bias;
        v = v > 0.f ? v : 0.f;
        *hp = v;
        hb[(size_t)row * H + col] = f2bf(v);
      }
    }
  }
}

// ---------------- global mean pool ----------------

__global__ __launch_bounds__(256) void reduce_mean_k(const float* __restrict__ h,
                                                     float* __restrict__ gsum, int n) {
  __shared__ float s[256];
  int col  = threadIdx.x & 127;
  int half = threadIdx.x >> 7;
  float acc = 0.f;
  for (int row = blockIdx.x * 2 + half; row < n; row += gridDim.x * 2)
    acc += h[(size_t)row * H + col];
  s[threadIdx.x] = acc;
  __syncthreads();
  if (threadIdx.x < 128) atomicAdd(&gsum[col], s[col] + s[col + 128]);
}

// ---------------- MLP head ----------------

__global__ __launch_bounds__(256) void mlp_k(const float* __restrict__ gsum,
                                             const float* __restrict__ W1,
                                             const float* __restrict__ b1,
                                             const float* __restrict__ W2,
                                             const float* __restrict__ b2,
                                             float* __restrict__ out, float invN) {
  __shared__ float g[H];
  __shared__ float hid[H];
  int tid = threadIdx.x;
  if (tid < H) g[tid] = gsum[tid] * invN;
  __syncthreads();
  if (tid < H) {
    float acc = b1[tid];
    for (int k = 0; k < H; ++k) acc += g[k] * W1[k * H + tid];
    hid[tid] = acc > 0.f ? acc : 0.f;
  }
  __syncthreads();
  float acc = b2[tid];
  for (int k = 0; k < H; ++k) acc += hid[k] * W2[k * 256 + tid];
  out[tid] = acc;
}

// ---------------- launcher ----------------

extern "C" void kernel_launch(void* const* d_in, const int* in_sizes, int n_in,
                              void* d_out, int out_size, void* d_ws, size_t ws_size,
                              hipStream_t stream) {
  const float* x  = (const float*)d_in[0];
  const int*   src = (const int*)d_in[1];
  const int*   dst = (const int*)d_in[2];
  const float* Wp = (const float*)d_in[3];
  const float* bp = (const float*)d_in[4];
  const float* Wg = (const float*)d_in[5];
  const float* bg = (const float*)d_in[6];
  const float* W1 = (const float*)d_in[7];
  const float* b1 = (const float*)d_in[8];
  const float* W2 = (const float*)d_in[9];
  const float* b2 = (const float*)d_in[10];
  float* out = (float*)d_out;

  const int N = in_sizes[0] / ND;   // 50000
  const int E = in_sizes[1];        // 800000
  const int N_pad = ((N + TILE_R - 1) / TILE_R) * TILE_R;  // 50048
  const size_t NH = (size_t)N_pad * H;

  char* p = (char*)d_ws;
  float* h = (float*)p;                 p += NH * sizeof(float);
  unsigned short* hb = (unsigned short*)p;   p += NH * sizeof(unsigned short);
  unsigned short* msgb = (unsigned short*)p; p += NH * sizeof(unsigned short);
  unsigned short* wfrag = (unsigned short*)p; p += 3 * 2048 * 8 * sizeof(unsigned short);
  unsigned short* wpfrag = (unsigned short*)p; p += 1024 * 8 * sizeof(unsigned short);
  int*   off  = (int*)p;   p += (size_t)(N + 1) * sizeof(int);
  int*   cur  = (int*)p;   p += (size_t)N * sizeof(int);
  int*   ssrc = (int*)p;   p += (size_t)E * sizeof(int);
  float* gsum = (float*)p; p += H * sizeof(float);
  int*   bsums= (int*)p;   p += 256 * sizeof(int);

  // xb (bf16 x, N_pad x 64) aliases msgb: proj reads xb before any aggregate
  // writes msgb (stream-ordered), and msgb (NH shorts) >= xb (NH/2 shorts).
  unsigned short* xb = msgb;

  const int nb = (N + SCAN_B - 1) / SCAN_B;
  const int ntiles = N_pad / TILE_R;    // 782

  // CSR build
  hipMemsetAsync(cur, 0, (size_t)N * sizeof(int), stream);
  count_deg_k<<<(E + 255) / 256, 256, 0, stream>>>(dst, cur, E);
  scan1_k<<<nb, SCAN_B, 0, stream>>>(cur, off, bsums, N);
  scan2_k<<<1, SCAN_B, 0, stream>>>(bsums, nb);
  scan3_k<<<nb, SCAN_B, 0, stream>>>(off, bsums, cur, N, E);
  scatter_k<<<(E + 255) / 256, 256, 0, stream>>>(src, dst, cur, ssrc, E);

  // weight prep + x cast
  prep_wfrag_k<<<3, 256, 0, stream>>>(Wg, wfrag);
  prep_wpfrag_k<<<1, 256, 0, stream>>>(Wp, wpfrag);
  cast_bf_k<<<(N * ND / 4 + 255) / 256, 256, 0, stream>>>(x, xb, N * ND / 4);

  // node projection (MFMA)
  node_proj_mfma_k<<<ntiles, 256, 0, stream>>>(xb, wpfrag, bp, h, hb, N);

  // 3 GNN layers
  for (int l = 0; l < 3; ++l) {
    aggregate_bf_k<<<(N + 7) / 8, 256, 0, stream>>>(hb, off, ssrc, msgb, N);
    layer_update_mfma_k<<<ntiles, 256, 0, stream>>>(h, hb, msgb,
                                                    wfrag + (size_t)l * 2048 * 8,
                                                    bg + (size_t)l * H, N);
  }

  // mean pool + MLP head
  hipMemsetAsync(gsum, 0, H * sizeof(float), stream);
  reduce_mean_k<<<256, 256, 0, stream>>>(h, gsum, N);
  mlp_k<<<1, 256, 0, stream>>>(gsum, W1, b1, W2, b2, out, 1.0f / (float)N);
}